// Round 10
// baseline (213.423 us; speedup 1.0000x reference)
//
#include <hip/hip_runtime.h>
#include <hip/hip_bf16.h>
#include <cmath>

#define S_LEN 2048
#define D_MODEL 2048
#define N_HEADS 16
#define Q_LORA 1536
#define KV_LORA 512
#define NOPE 128
#define ROPE_D 64
#define VD 128
#define QHD 192
#define AC_W 2112  // fused a-proj output width: 1536 q_a + 576 ckv

typedef __attribute__((ext_vector_type(8))) short bf16x8;
typedef __attribute__((ext_vector_type(4))) float f32x4;
typedef __attribute__((ext_vector_type(16))) float f32x16;
typedef __attribute__((ext_vector_type(4))) unsigned short u16x4;

static __device__ __forceinline__ unsigned short f2u(float x) {
  union { float f; unsigned u; } v; v.f = x;
  unsigned r = v.u + 0x7fffu + ((v.u >> 16) & 1u);  // RNE
  return (unsigned short)(r >> 16);
}
static __device__ __forceinline__ unsigned short f2u_fast(float x) {  // round-half-up, x>=0
  union { float f; unsigned u; } v; v.f = x;
  return (unsigned short)((v.u + 0x8000u) >> 16);
}
static __device__ __forceinline__ float u2f(unsigned short x) {
  union { unsigned u; float f; } v; v.u = ((unsigned)x) << 16;
  return v.f;
}

#define AS1 __attribute__((address_space(1)))
#define AS3 __attribute__((address_space(3)))
static __device__ __forceinline__ void gload_lds16(const unsigned short* g, unsigned short* l) {
  __builtin_amdgcn_global_load_lds((const AS1 unsigned int*)g, (AS3 unsigned int*)l, 16, 0, 0);
}

// ---------------------------------------------------------------------------
// f32 -> bf16 convert (optionally scaled). n4 = elements/4.
// ---------------------------------------------------------------------------
__global__ __launch_bounds__(256) void conv_bf16(const float* __restrict__ src,
                                                 unsigned short* __restrict__ dst,
                                                 int n4, float scale) {
  for (int i = blockIdx.x * 256 + threadIdx.x; i < n4; i += gridDim.x * 256) {
    const float4 v = ((const float4*)src)[i];
    u16x4 o;
    o[0] = f2u(v.x * scale); o[1] = f2u(v.y * scale);
    o[2] = f2u(v.z * scale); o[3] = f2u(v.w * scale);
    ((u16x4*)dst)[i] = o;
  }
}

// two-segment variant (fused q_a_w + kv_a_w conversion)
__global__ __launch_bounds__(256) void conv2_bf16(const float* __restrict__ srcA, int n4a,
                                                  const float* __restrict__ srcB, int n4total,
                                                  unsigned short* __restrict__ dst) {
  for (int i = blockIdx.x * 256 + threadIdx.x; i < n4total; i += gridDim.x * 256) {
    const float4 v = (i < n4a) ? ((const float4*)srcA)[i] : ((const float4*)srcB)[i - n4a];
    u16x4 o;
    o[0] = f2u(v.x); o[1] = f2u(v.y); o[2] = f2u(v.z); o[3] = f2u(v.w);
    ((u16x4*)dst)[i] = o;
  }
}

// ---------------------------------------------------------------------------
// bf16 MFMA GEMM: C[M,N] = A[M,K] @ W[N,K]^T. 128x64 tile, BK=64, 4 waves
// (each 64x32 output), double-buffered LDS (48 KB), one barrier per 64-k
// step, XOR-swizzled (pre-swizzled global source + same XOR on ds_read).
// (unchanged from round 9)
// ---------------------------------------------------------------------------
template <int MODE>
__global__ __launch_bounds__(256) void gemm_mfma(const unsigned short* __restrict__ A,
                                                 const unsigned short* __restrict__ W,
                                                 void* __restrict__ Cv,
                                                 unsigned short* __restrict__ C2,
                                                 int N, int K) {
  __shared__ unsigned short As[2][8192];  // 128 x 64 bf16
  __shared__ unsigned short Ws[2][4096];  //  64 x 64 bf16
  const int tid = threadIdx.x;
  const int wave = tid >> 6, lane = tid & 63;
  const int col16 = lane & 15, g = lane >> 4;
  const int arow = blockIdx.y * 128, wrow = blockIdx.x * 64;
  const int wm = (wave >> 1) * 64, wn = (wave & 1) * 32;

  const unsigned short* gA[4];
  const unsigned short* gW[2];
  int dA[4], dW[2];
#pragma unroll
  for (int i = 0; i < 4; ++i) {
    const int c = i * 256 + tid;
    const int r = c >> 3, sl = c & 7;
    gA[i] = A + (size_t)(arow + r) * K + (sl ^ (r & 7)) * 8;
    dA[i] = c * 8;
  }
#pragma unroll
  for (int i = 0; i < 2; ++i) {
    const int c = i * 256 + tid;
    const int r = c >> 3, sl = c & 7;
    gW[i] = W + (size_t)(wrow + r) * K + (sl ^ (r & 7)) * 8;
    dW[i] = c * 8;
  }

  f32x4 acc[4][2];
#pragma unroll
  for (int i = 0; i < 4; ++i)
#pragma unroll
    for (int j = 0; j < 2; ++j) acc[i][j] = (f32x4){0.f, 0.f, 0.f, 0.f};

#pragma unroll
  for (int i = 0; i < 4; ++i) gload_lds16(gA[i], &As[0][dA[i]]);
#pragma unroll
  for (int i = 0; i < 2; ++i) gload_lds16(gW[i], &Ws[0][dW[i]]);

  int cur = 0;
  for (int k0 = 0; k0 < K; k0 += 64) {
    __syncthreads();
    if (k0 + 64 < K) {
      const int b = cur ^ 1, kk = k0 + 64;
#pragma unroll
      for (int i = 0; i < 4; ++i) gload_lds16(gA[i] + kk, &As[b][dA[i]]);
#pragma unroll
      for (int i = 0; i < 2; ++i) gload_lds16(gW[i] + kk, &Ws[b][dW[i]]);
    }
#pragma unroll
    for (int kh = 0; kh < 2; ++kh) {
      bf16x8 af[4], bfr[2];
#pragma unroll
      for (int i = 0; i < 4; ++i) {
        const int row = wm + i * 16 + col16;
        af[i] = *(const bf16x8*)(&As[cur][row * 64 + (((kh * 4 + g) ^ (row & 7)) * 8)]);
      }
#pragma unroll
      for (int j = 0; j < 2; ++j) {
        const int row = wn + j * 16 + col16;
        bfr[j] = *(const bf16x8*)(&Ws[cur][row * 64 + (((kh * 4 + g) ^ (row & 7)) * 8)]);
      }
#pragma unroll
      for (int i = 0; i < 4; ++i)
#pragma unroll
        for (int j = 0; j < 2; ++j)
          acc[i][j] = __builtin_amdgcn_mfma_f32_16x16x32_bf16(af[i], bfr[j], acc[i][j], 0, 0, 0);
    }
    cur ^= 1;
  }

#pragma unroll
  for (int i = 0; i < 4; ++i)
#pragma unroll
    for (int j = 0; j < 2; ++j) {
      const int col = wrow + wn + j * 16 + col16;
      const int row0 = arow + wm + i * 16 + g * 4;
#pragma unroll
      for (int r = 0; r < 4; ++r) {
        if constexpr (MODE == 0)
          ((float*)Cv)[(size_t)(row0 + r) * N + col] = acc[i][j][r];
        else if constexpr (MODE == 1)
          ((unsigned short*)Cv)[(size_t)(row0 + r) * N + col] = f2u(acc[i][j][r]);
        else {
          const int hh = col >> 8, d = col & 255;
          if (d < NOPE)
            C2[((size_t)hh * S_LEN + row0 + r) * QHD + d] = f2u(acc[i][j][r]);
          else
            ((unsigned short*)Cv)[(size_t)(row0 + r) * (N_HEADS * 256) + col] = f2u(acc[i][j][r]);
        }
      }
    }
}

// ---------------------------------------------------------------------------
// RMSNorm over last dim, f32 in -> bf16 out.
// ---------------------------------------------------------------------------
__global__ __launch_bounds__(256) void rmsnorm_kernel(const float* __restrict__ src, int src_ld,
                                                      const float* __restrict__ w,
                                                      unsigned short* __restrict__ dst, int dst_ld,
                                                      int dim) {
  const int row = blockIdx.x;
  const float* x = src + (size_t)row * src_ld;
  float ss = 0.f;
  for (int i = threadIdx.x; i < dim; i += 256) {
    float v = x[i];
    ss += v * v;
  }
#pragma unroll
  for (int off = 32; off; off >>= 1) ss += __shfl_xor(ss, off);
  __shared__ float red[4];
  const int wv = threadIdx.x >> 6, ln = threadIdx.x & 63;
  if (ln == 0) red[wv] = ss;
  __syncthreads();
  const float tot = red[0] + red[1] + red[2] + red[3];
  const float scale = rsqrtf(tot / (float)dim + 1e-6f);
  for (int i = threadIdx.x; i < dim; i += 256) {
    dst[(size_t)row * dst_ld + i] = f2u(w[i] * (x[i] * scale));
  }
}

// ---------------------------------------------------------------------------
// RoPE: q_pe slices of bf16 qbuf in place; k_pe -> broadcast into Kb.
// ---------------------------------------------------------------------------
__global__ void rope_kernel(unsigned short* __restrict__ q, const float* __restrict__ ac,
                            unsigned short* __restrict__ Kb, const int* __restrict__ pos_ids) {
  const int s = blockIdx.x;
  const int j = threadIdx.x;  // 0..31
  const float t = (float)pos_ids[s];
  const float invf = powf(50000.0f, -(float)(2 * j) / 64.0f);
  const float ang = t * invf;
  const float c = cosf(ang), sn = sinf(ang);
  for (int h = 0; h < N_HEADS; ++h) {
    unsigned short* base = q + (size_t)s * (N_HEADS * QHD) + h * QHD + NOPE;
    const float x0 = u2f(base[2 * j]), x1 = u2f(base[2 * j + 1]);
    __syncthreads();
    base[j] = f2u(x0 * c - x1 * sn);
    base[32 + j] = f2u(x1 * c + x0 * sn);
    __syncthreads();
  }
  const float* kb = ac + (size_t)s * AC_W + 2048;
  const unsigned short r0 = f2u(kb[2 * j] * c - kb[2 * j + 1] * sn);
  const unsigned short r1 = f2u(kb[2 * j + 1] * c + kb[2 * j] * sn);
#pragma unroll
  for (int h = 0; h < N_HEADS; ++h) {
    unsigned short* kd = Kb + ((size_t)h * S_LEN + s) * QHD + NOPE;
    kd[j] = r0;
    kd[32 + j] = r1;
  }
}

// ---------------------------------------------------------------------------
// V transpose + crow-permuted column order within each 32-kv block:
// stored position p = g16*16 + 8*h2 + j  holds  k = g16*16 + 4*h2 + (j&3) + 8*(j>>2)
// (the 32x32 MFMA C-row order) so PV A-fragments are single contiguous 16B reads.
// ---------------------------------------------------------------------------
__global__ __launch_bounds__(256) void build_vt(const unsigned short* __restrict__ kv,
                                                unsigned short* __restrict__ Vt) {
  __shared__ unsigned short t[32][33];
  const int s0 = blockIdx.x * 32, d0 = blockIdx.y * 32, h = blockIdx.z;
  const int tx = threadIdx.x & 31, ty = threadIdx.x >> 5;
#pragma unroll
  for (int i = 0; i < 4; ++i) {
    const int s = s0 + ty + i * 8;
    t[ty + i * 8][tx] = kv[(size_t)s * (N_HEADS * 256) + h * 256 + NOPE + d0 + tx];
  }
  __syncthreads();
  const int g16 = tx >> 4, k16 = tx & 15;
  const int h2 = (k16 >> 2) & 1;
  const int jj = (k16 & 3) + 4 * ((k16 >> 3) & 1);
  const int p = g16 * 16 + h2 * 8 + jj;
#pragma unroll
  for (int i = 0; i < 4; ++i) {
    const int d = d0 + ty + i * 8;
    Vt[((size_t)h * VD + d) * S_LEN + s0 + p] = t[tx][ty + i * 8];
  }
}

// ---------------------------------------------------------------------------
// Split-4 MFMA flash attention with 32x32x16 MFMA. Block = 4 waves x 32 q =
// 128 rows; split s takes 32-kv tiles j == s (mod 4) -> exactly t+1 tiles per
// split (perfect causal balance). Grid 1024 -> 4 blocks/CU at 40 KB LDS.
// QK: C = mfma32(K, Q) -> C col=lane&31=q, row k = (r&3)+8(r>>2)+4(lane>>5).
// PV: O^T = mfma32(V^T, P): B-frags are the QK C-regs (0..7 | 8..15) in-lane;
// V^T stored crow-permuted so A-frags are contiguous 16B reads (identical-pi
// on both operands -> correct under any internal k-map).
// Softmax: in-lane max over 16 regs + ONE shfl_xor(32); exp2 domain;
// defer-max THR=8. bf16 partials + (m,l) per split; combine4 merges.
// ---------------------------------------------------------------------------
__global__ __launch_bounds__(256) void flash_attn(const unsigned short* __restrict__ Q,   // (S,3072) pre-scaled
                                                  const unsigned short* __restrict__ Kb,  // (H,S,192)
                                                  const unsigned short* __restrict__ Vt,  // (H,128,S) crow-permuted
                                                  unsigned short* __restrict__ Pb,        // (S,4,16,128) bf16 partials
                                                  float2* __restrict__ mlb) {             // (S,4,16) {m,l}
  __shared__ unsigned short Ks[2][32 * QHD];   // 2 x 12 KB
  __shared__ unsigned short Vs[2][VD * 32];    // 2 x  8 KB
  const int tid = threadIdx.x;
  const int wave = tid >> 6, lane = tid & 63;
  const int q5 = lane & 31, h2 = lane >> 5;
  const int lin = (int)blockIdx.x;                    // 0..1023
  const int h = ((lin & 7) << 1) | ((lin >> 3) & 1);  // XCD owns a head pair
  const int s = (lin >> 4) & 3;                       // k-split
  const int z = lin >> 6;                             // 0..15
  const int za = z >> 2, zb = z & 3;
  const int t = 4 * za + ((za + zb) & 3);             // co-resident quad sums to 34
  const int qw = t * 128 + wave * 32;
  const int qr = qw + q5;

  bf16x8 qf[12];
  {
    const unsigned short* qrow = Q + (size_t)qr * (N_HEADS * QHD) + h * QHD + h2 * 8;
#pragma unroll
    for (int i = 0; i < 12; ++i) qf[i] = *(const bf16x8*)(qrow + i * 16);
  }

  const unsigned short* KbH = Kb + (size_t)h * S_LEN * QHD;
  const unsigned short* VtH = Vt + (size_t)h * VD * S_LEN;

  // staging source offsets (pre-swizzled slots; fixed across tiles)
  int eK[3], eV[2];
#pragma unroll
  for (int i = 0; i < 3; ++i) {                 // 768 K chunks of 16B
    const int c = i * 256 + tid;
    const int r = c / 24, sl = c - r * 24;
    eK[i] = r * QHD + (((sl & 24) | ((sl & 7) ^ (r & 7)))) * 8;
  }
#pragma unroll
  for (int i = 0; i < 2; ++i) {                 // 512 V chunks of 16B
    const int c = i * 256 + tid;
    const int d = c >> 2, sl = c & 3;
    eV[i] = d * S_LEN + ((sl ^ (d & 3))) * 8;
  }

  // ds_read offsets
  int xK[12];
#pragma unroll
  for (int i = 0; i < 12; ++i) {
    const int sg = 2 * i + h2;                  // canonical 16B slot (0..23)
    xK[i] = q5 * QHD + (((sg & 24) | ((sg & 7) ^ (q5 & 7)))) * 8;
  }
  int xV[2];
#pragma unroll
  for (int i = 0; i < 2; ++i) xV[i] = q5 * 32 + (((i * 2 + h2) ^ (q5 & 3))) * 8;

  f32x16 o[4];
#pragma unroll
  for (int i = 0; i < 4; ++i)
#pragma unroll
    for (int r = 0; r < 16; ++r) o[i][r] = 0.f;
  float m = -1e30f, l = 0.f;

  const int nT = t + 1;  // tiles j = 4*it + s

  // prologue: stage tile j=s into buffer 0
  {
    const unsigned short* kp = KbH + (size_t)s * 32 * QHD;
    const unsigned short* vp = VtH + s * 32;
#pragma unroll
    for (int i = 0; i < 3; ++i) gload_lds16(kp + eK[i], &Ks[0][(i * 256 + tid) * 8]);
#pragma unroll
    for (int i = 0; i < 2; ++i) gload_lds16(vp + eV[i], &Vs[0][(i * 256 + tid) * 8]);
  }

  for (int it = 0; it < nT; ++it) {
    __syncthreads();
    if (it + 1 < nT) {
      const int jn = 4 * (it + 1) + s;
      const unsigned short* kp = KbH + (size_t)jn * 32 * QHD;
      const unsigned short* vp = VtH + jn * 32;
      const int b = (it + 1) & 1;
#pragma unroll
      for (int i = 0; i < 3; ++i) gload_lds16(kp + eK[i], &Ks[b][(i * 256 + tid) * 8]);
#pragma unroll
      for (int i = 0; i < 2; ++i) gload_lds16(vp + eV[i], &Vs[b][(i * 256 + tid) * 8]);
    }
    const int k0 = 32 * (4 * it + s);
    if (k0 <= qw + 31) {   // wave-uniform compute guard
      const unsigned short* Ksc = Ks[it & 1];
      const unsigned short* Vsc = Vs[it & 1];

      f32x16 c;
#pragma unroll
      for (int r = 0; r < 16; ++r) c[r] = 0.f;
      __builtin_amdgcn_s_setprio(1);
#pragma unroll
      for (int dt = 0; dt < 12; ++dt) {
        const bf16x8 a = *(const bf16x8*)(Ksc + xK[dt]);
        c = __builtin_amdgcn_mfma_f32_32x32x16_bf16(a, qf[dt], c, 0, 0, 0);
      }
      __builtin_amdgcn_s_setprio(0);

      // causal mask only on diagonal tiles (k = k0 + (r&3) + 8*(r>>2) + 4*h2)
      if (k0 + 31 > qw) {
#pragma unroll
        for (int r = 0; r < 16; ++r) {
          const int kk = k0 + (r & 3) + 8 * (r >> 2) + 4 * h2;
          if (kk > qr) c[r] = -1e30f;
        }
      }
      float bm = c[0];
#pragma unroll
      for (int r = 1; r < 16; ++r) bm = fmaxf(bm, c[r]);
      bm = fmaxf(bm, __shfl_xor(bm, 32));
      const bool skip = __all(bm <= m + 8.f);   // defer-max: p bounded by 2^8
      const float mn = skip ? m : fmaxf(m, bm);
      float ps = 0.f;
      bf16x8 pb0, pb1;
#pragma unroll
      for (int r = 0; r < 8; ++r) {
        const float p0 = exp2f(c[r] - mn);
        const float p1 = exp2f(c[8 + r] - mn);
        ps += p0 + p1;
        pb0[r] = (short)f2u_fast(p0);
        pb1[r] = (short)f2u_fast(p1);
      }
      ps += __shfl_xor(ps, 32);
      if (skip) {
        l += ps;
      } else {
        const float corr = exp2f(m - mn);
        l = l * corr + ps;
        m = mn;
#pragma unroll
        for (int i = 0; i < 4; ++i)
#pragma unroll
          for (int r = 0; r < 16; ++r) o[i][r] *= corr;
      }
      __builtin_amdgcn_s_setprio(1);
#pragma unroll
      for (int db = 0; db < 4; ++db) {
        const bf16x8 va0 = *(const bf16x8*)(Vsc + db * 1024 + xV[0]);
        o[db] = __builtin_amdgcn_mfma_f32_32x32x16_bf16(va0, pb0, o[db], 0, 0, 0);
        const bf16x8 va1 = *(const bf16x8*)(Vsc + db * 1024 + xV[1]);
        o[db] = __builtin_amdgcn_mfma_f32_32x32x16_bf16(va1, pb1, o[db], 0, 0, 0);
      }
      __builtin_amdgcn_s_setprio(0);
    }
  }

  // epilogue: bf16 partials (d = db*32 + 4*h2 + 8*rq + (0..3)) + (m,l)
  unsigned short* pr = Pb + (((size_t)qr * 4 + s) * N_HEADS + h) * VD;
#pragma unroll
  for (int db = 0; db < 4; ++db)
#pragma unroll
    for (int rq = 0; rq < 4; ++rq) {
      const int d0 = db * 32 + 4 * h2 + 8 * rq;
      u16x4 w4;
      w4[0] = f2u(o[db][rq * 4 + 0]);
      w4[1] = f2u(o[db][rq * 4 + 1]);
      w4[2] = f2u(o[db][rq * 4 + 2]);
      w4[3] = f2u(o[db][rq * 4 + 3]);
      *(uint2*)(pr + d0) = __builtin_bit_cast(uint2, w4);
    }
  if (h2 == 0) mlb[((size_t)qr * 4 + s) * N_HEADS + h] = make_float2(m, l);
}

// ---------------------------------------------------------------------------
// Merge the 4 k-splits: out = sum_s w_s*O_s / sum_s w_s*l_s, bf16.
// chunk = (q, h, d8): 2048*16*16 chunks of 8 elements.
// ---------------------------------------------------------------------------
__global__ __launch_bounds__(256) void combine4(const unsigned short* __restrict__ Pb,
                                                const float2* __restrict__ mlb,
                                                unsigned short* __restrict__ outb) {
  const int idx = blockIdx.x * 256 + threadIdx.x;  // exactly 524288
  const int d8 = idx & 15, hq = idx >> 4;
  const int h = hq & 15, q = hq >> 4;
  float2 ml[4];
  float M = -1e30f;
#pragma unroll
  for (int s = 0; s < 4; ++s) {
    ml[s] = mlb[((size_t)q * 4 + s) * N_HEADS + h];
    M = fmaxf(M, ml[s].x);
  }
  float w[4], den = 0.f;
#pragma unroll
  for (int s = 0; s < 4; ++s) {
    w[s] = exp2f(ml[s].x - M);
    den += w[s] * ml[s].y;
  }
  const float inv = 1.f / den;
  float acc[8] = {};
#pragma unroll
  for (int s = 0; s < 4; ++s) {
    const bf16x8 v = *(const bf16x8*)(Pb + (((size_t)q * 4 + s) * N_HEADS + h) * VD + d8 * 8);
    const float ws = w[s] * inv;
#pragma unroll
    for (int e = 0; e < 8; ++e) acc[e] += u2f((unsigned short)v[e]) * ws;
  }
  u16x4 o0, o1;
#pragma unroll
  for (int e = 0; e < 4; ++e) { o0[e] = f2u(acc[e]); o1[e] = f2u(acc[4 + e]); }
  unsigned short* dst = outb + ((size_t)q * N_HEADS + h) * VD + d8 * 8;
  *(uint2*)(dst) = __builtin_bit_cast(uint2, o0);
  *(uint2*)(dst + 4) = __builtin_bit_cast(uint2, o1);
}

// ---------------------------------------------------------------------------
extern "C" void kernel_launch(void* const* d_in, const int* in_sizes, int n_in,
                              void* d_out, int out_size, void* d_ws, size_t ws_size,
                              hipStream_t stream) {
  const float* hidden    = (const float*)d_in[0];
  const int*   pos       = (const int*)d_in[1];
  const float* q_a_w     = (const float*)d_in[2];
  const float* q_a_ln_w  = (const float*)d_in[3];
  const float* q_b_w     = (const float*)d_in[4];
  const float* kv_a_w    = (const float*)d_in[5];
  const float* kv_a_ln_w = (const float*)d_in[6];
  const float* kv_b_w    = (const float*)d_in[7];
  const float* o_w       = (const float*)d_in[8];
  float* out = (float*)d_out;
  (void)in_sizes; (void)n_in; (void)out_size; (void)ws_size;

  // workspace layout (bytes); total ~94 MB
  char* base = (char*)d_ws;
  unsigned short* qbuf  = (unsigned short*)(base);              // S*3072 bf16  12.58MB
  unsigned short* kvbuf = (unsigned short*)(base + 12582912);   // S*4096 bf16  (V half)
  unsigned short* Pbuf  = (unsigned short*)(base + 12582912);   //   overlay: S*4*2048 bf16 = 33.55MB
  float2*         mlb   = (float2*)(base + 46137344);           //   overlay: S*4*16 float2 = 1MB (qan dead)
  float*          ac    = (float*)(base + 29360128);            // S*2112 f32   17.30MB
  unsigned short* qan   = (unsigned short*)(base + 46661632);   // S*1536 bf16   6.29MB
  unsigned short* ckvn  = (unsigned short*)(base + 52953088);   // S*512 bf16    2.10MB
  unsigned short* Hb    = (unsigned short*)(base + 55050240);   // S*2048 bf16   8.39MB
  unsigned short* Vt    = (unsigned short*)(base + 55050240);   //   overlay (Hb dead after a-proj)
  unsigned short* wbuf  = (unsigned short*)(base + 63438848);   // 4.72M bf16    9.44MB
  unsigned short* attnb = (unsigned short*)(base + 72876032);   // S*2048 bf16   8.39MB
  unsigned short* Kb    = (unsigned short*)(base + 81264640);   // 16*S*192 bf16 12.58MB

  const dim3 b256(256);
  // 192^-0.5 * log2(e): scores come out of QK^T directly in log2 domain
  const float qscale = 0.07216878364870323f * 1.4426950408889634f;

  conv_bf16<<<2048, b256, 0, stream>>>(hidden, Hb, (S_LEN * D_MODEL) / 4, 1.f);

  // fused a-proj: W = [q_a_w ; kv_a_w] (2112 x 2048), C = ac f32 (S x 2112)
  conv2_bf16<<<2048, b256, 0, stream>>>(q_a_w, (Q_LORA * D_MODEL) / 4,
                                        kv_a_w, (AC_W * D_MODEL) / 4, wbuf);
  gemm_mfma<0><<<dim3(AC_W / 64, S_LEN / 128), b256, 0, stream>>>(Hb, wbuf, ac, nullptr, AC_W, D_MODEL);

  rmsnorm_kernel<<<S_LEN, b256, 0, stream>>>(ac, AC_W, q_a_ln_w, qan, Q_LORA, Q_LORA);
  rmsnorm_kernel<<<S_LEN, b256, 0, stream>>>(ac + Q_LORA, AC_W, kv_a_ln_w, ckvn, KV_LORA, KV_LORA);

  // qbuf = qan @ (qscale*q_b_w)^T   (bf16 out)
  conv_bf16<<<2048, b256, 0, stream>>>(q_b_w, wbuf, (N_HEADS * QHD * Q_LORA) / 4, qscale);
  gemm_mfma<1><<<dim3(N_HEADS * QHD / 64, S_LEN / 128), b256, 0, stream>>>(qan, wbuf, qbuf, nullptr, N_HEADS * QHD, Q_LORA);

  // kv_b: k_nope -> Kb directly, values -> kvbuf
  conv_bf16<<<2048, b256, 0, stream>>>(kv_b_w, wbuf, (N_HEADS * 256 * KV_LORA) / 4, 1.f);
  gemm_mfma<2><<<dim3(N_HEADS * 256 / 64, S_LEN / 128), b256, 0, stream>>>(ckvn, wbuf, kvbuf, Kb, N_HEADS * 256, KV_LORA);

  // rope: qbuf q_pe in place; k_pe -> Kb cols 128..192 (all heads)
  rope_kernel<<<S_LEN, 32, 0, stream>>>(qbuf, ac, Kb, pos);

  build_vt<<<dim3(S_LEN / 32, VD / 32, N_HEADS), b256, 0, stream>>>(kvbuf, Vt);

  // split-4 flash (partials over kvbuf/ac region — dead) + combine
  flash_attn<<<dim3(1024), b256, 0, stream>>>(qbuf, Kb, Vt, Pbuf, mlb);
  combine4<<<2048, b256, 0, stream>>>(Pbuf, mlb, attnb);

  conv_bf16<<<2048, b256, 0, stream>>>(o_w, wbuf, (D_MODEL * N_HEADS * VD) / 4, 1.f);
  gemm_mfma<0><<<dim3(D_MODEL / 64, S_LEN / 128), b256, 0, stream>>>(attnb, wbuf, out, nullptr, D_MODEL, N_HEADS * VD);
}